// Round 2
// baseline (179.156 us; speedup 1.0000x reference)
//
#include <hip/hip_runtime.h>
#include <hip/hip_bf16.h>

typedef unsigned short ushort_t;
typedef __attribute__((ext_vector_type(8))) short short8;
typedef __attribute__((ext_vector_type(8))) unsigned short u16x8;
typedef __attribute__((ext_vector_type(4))) float f32x4;

#define BETA 0.4f
#define EPS_C 0.05f
#define NB 8192
#define NH 1024
#define NL 2048
#define NC 5

static __device__ __forceinline__ float b2f(unsigned short u) {
    union { unsigned int i; float f; } x; x.i = ((unsigned int)u) << 16; return x.f;
}
static __device__ __forceinline__ unsigned short f2b(float f) {
    union { float f; unsigned int i; } x; x.f = f;
    unsigned int i = x.i;
    unsigned int r = (i + 0x7FFFu + ((i >> 16) & 1u)) >> 16;
    return (unsigned short)r;
}

static __device__ __forceinline__ void gload16(const ushort_t* g, ushort_t* l) {
    __builtin_amdgcn_global_load_lds((const __attribute__((address_space(1))) void*)g,
                                     (__attribute__((address_space(3))) void*)l, 16, 0, 0);
}

#define CFENCE() asm volatile("" ::: "memory")

// ---------------- conversion kernels ----------------
__global__ __launch_bounds__(256) void cvt_kernel(const float* __restrict__ in,
                                                  ushort_t* __restrict__ out, long n) {
    long i = ((long)blockIdx.x * 256 + threadIdx.x) * 8;
    if (i >= n) return;
    const float4 a = *(const float4*)(in + i);
    const float4 b = *(const float4*)(in + i + 4);
    u16x8 o;
    o[0] = f2b(a.x); o[1] = f2b(a.y); o[2] = f2b(a.z); o[3] = f2b(a.w);
    o[4] = f2b(b.x); o[5] = f2b(b.y); o[6] = f2b(b.z); o[7] = f2b(b.w);
    *(u16x8*)(out + i) = o;
}

// W1 [2048,1024] -> W1T bf16 [1024,2048]
__global__ __launch_bounds__(256) void trans_kernel(const float* __restrict__ W1,
                                                    ushort_t* __restrict__ W1Tb) {
    __shared__ float tile[32][33];
    const int tx = threadIdx.x & 31, ty = threadIdx.x >> 5;
    const int k0 = blockIdx.x * 32, n0 = blockIdx.y * 32;
#pragma unroll
    for (int i = 0; i < 4; ++i)
        tile[ty + i * 8][tx] = W1[(size_t)(k0 + ty + i * 8) * NH + n0 + tx];
    __syncthreads();
#pragma unroll
    for (int i = 0; i < 4; ++i)
        W1Tb[(size_t)(n0 + ty + i * 8) * NL + k0 + tx] = f2b(tile[tx][ty + i * 8]);
}

// ---------------- 8-phase pipelined GEMM (C = A @ Bt^T) ----------------
// EPI 0: GEMM1  A=[8192,2048] Bt=[1024,2048]  BM=256 BN=128, tanh epilogue -> hout
// EPI 1: GEMM2  A=[8192,1024] Bt=[2048,1024]  BM=256 BN=256, |.| row partials -> partout
template <int EPI>
__global__ __launch_bounds__(512, 2) void gemm8p(const ushort_t* __restrict__ A,
                                                 const ushort_t* __restrict__ Bt,
                                                 const float* __restrict__ b1,
                                                 ushort_t* __restrict__ hout,
                                                 float* __restrict__ partout) {
    constexpr int BN_T = (EPI == 0) ? 128 : 256;
    constexpr int K    = (EPI == 0) ? 2048 : 1024;
    constexpr int NOUT = (EPI == 0) ? 1024 : 2048;
    constexpr int NT   = K / 64;                 // K-tiles of 64
    constexpr int NPH  = (EPI == 0) ? 2 : 4;     // phases per K-tile
    constexpr int MPP  = 8 / NPH;                // m-frags per phase
    constexpr int NREP = BN_T / 64;              // n-frags per wave

    __shared__ ushort_t As[2][16384];            // 2 x 256x64 bf16 = 64 KB
    __shared__ ushort_t Bs[2][BN_T * 64];        // 32 or 64 KB

    const int tid = threadIdx.x;
    const int wv = tid >> 6, lane = tid & 63;
    const int wm = wv >> 2, wn = wv & 3;         // 2M x 4N waves
    const int fr = lane & 15, fg = lane >> 4;
    const int swz = (lane & 7) << 4;             // XOR swizzle bits (involution)
    const int cbb = fg << 4;

    // XCD-aware remap: 256 blocks, each XCD gets one bn-panel (32 consecutive wg)
    const int wg = (blockIdx.x & 7) * 32 + (blockIdx.x >> 3);
    const int bm0 = (wg & 31) * 256;
    const int bnIdx = wg >> 5;
    const int bn0 = bnIdx * BN_T;

    const int srow = lane >> 3;                       // staging row-in-8
    const int scol = ((lane & 7) ^ srow) << 3;        // pre-swizzled source col (elems)

    auto stA = [&](int buf, int kt, int half) {
#pragma unroll
        for (int c = 0; c < 2; ++c) {
            const int row = wv * 16 + c * 8 + srow;
            const ushort_t* g = A + (size_t)(bm0 + half * 128 + row) * K + kt * 64 + scol;
            gload16(g, &As[buf][half * 8192 + wv * 1024 + c * 512]);
        }
    };
    auto stB = [&](int buf, int kt, int half) {
#pragma unroll
        for (int c = 0; c < 2; ++c) {
            const int row = wv * 16 + c * 8 + srow;
            const ushort_t* g = Bt + (size_t)(bn0 + half * 128 + row) * K + kt * 64 + scol;
            gload16(g, &Bs[buf][half * 8192 + wv * 1024 + c * 512]);
        }
    };
    auto ldA = [&](int buf, int mf, int ks) -> short8 {
        const int rowt = wm * 128 + mf * 16 + fr;     // rowt&7 == lane&7
        return *(const short8*)((const char*)&As[buf][0] + rowt * 128 + (((ks << 6) + cbb) ^ swz));
    };
    auto ldB = [&](int buf, int nf, int ks) -> short8 {
        const int rowt = wn * (BN_T / 4) + nf * 16 + fr;
        return *(const short8*)((const char*)&Bs[buf][0] + rowt * 128 + (((ks << 6) + cbb) ^ swz));
    };

    f32x4 acc[8][NREP] = {};
    short8 bf[NREP][2];

    // prologue: stage K-tile 0 into buffer 0
    stA(0, 0, 0); stA(0, 0, 1);
    stB(0, 0, 0);
    if constexpr (EPI == 1) stB(0, 0, 1);

    for (int t = 0; t < NT; ++t) {
        const int cur = t & 1, nxt = cur ^ 1;
        const bool more = (t + 1 < NT);
#pragma unroll
        for (int p = 0; p < NPH; ++p) {
            // issue next-tile staging (spans barriers; counted vmcnt gates it)
            if (more) {
                if constexpr (EPI == 0) {
                    if (p == 0) { stA(nxt, t + 1, 0); stA(nxt, t + 1, 1); }
                    else        { stB(nxt, t + 1, 0); }
                } else {
                    if (p == 0)      stA(nxt, t + 1, 0);
                    else if (p == 1) stA(nxt, t + 1, 1);
                    else if (p == 2) stB(nxt, t + 1, 0);
                    else             stB(nxt, t + 1, 1);
                }
            }
            if (p == 0) {
                if (more) {
                    if constexpr (EPI == 0) asm volatile("s_waitcnt vmcnt(4)" ::: "memory");
                    else                    asm volatile("s_waitcnt vmcnt(2)" ::: "memory");
                } else {
                    asm volatile("s_waitcnt vmcnt(0)" ::: "memory");
                }
                CFENCE(); __builtin_amdgcn_s_barrier(); CFENCE();
#pragma unroll
                for (int n = 0; n < NREP; ++n)
#pragma unroll
                    for (int ks = 0; ks < 2; ++ks) bf[n][ks] = ldB(cur, n, ks);
            }
            short8 af[MPP][2];
#pragma unroll
            for (int i = 0; i < MPP; ++i)
#pragma unroll
                for (int ks = 0; ks < 2; ++ks) af[i][ks] = ldA(cur, p * MPP + i, ks);
            __builtin_amdgcn_s_setprio(1);
#pragma unroll
            for (int i = 0; i < MPP; ++i)
#pragma unroll
                for (int n = 0; n < NREP; ++n)
#pragma unroll
                    for (int ks = 0; ks < 2; ++ks)
                        acc[p * MPP + i][n] = __builtin_amdgcn_mfma_f32_16x16x32_bf16(
                            af[i][ks], bf[n][ks], acc[p * MPP + i][n], 0, 0, 0);
            __builtin_amdgcn_s_setprio(0);
            CFENCE(); __builtin_amdgcn_s_barrier(); CFENCE();
        }
    }

    if constexpr (EPI == 0) {
#pragma unroll
        for (int m = 0; m < 8; ++m)
#pragma unroll
            for (int n = 0; n < NREP; ++n) {
                const int col = bn0 + wn * 32 + n * 16 + fr;
                const float bb = b1[col];
                const size_t rbase = (size_t)(bm0 + wm * 128 + m * 16 + fg * 4) * NOUT + col;
#pragma unroll
                for (int r = 0; r < 4; ++r)
                    hout[rbase + (size_t)r * NOUT] = f2b(tanhf(acc[m][n][r] + bb));
            }
    } else {
        float* rsum = (float*)&As[0][0];  // LDS dead after K-loop; reuse (4 KB)
#pragma unroll
        for (int m = 0; m < 8; ++m)
#pragma unroll
            for (int r = 0; r < 4; ++r) {
                float s = 0.f;
#pragma unroll
                for (int n = 0; n < NREP; ++n) s += fabsf(acc[m][n][r]);
                s += __shfl_xor(s, 1); s += __shfl_xor(s, 2);
                s += __shfl_xor(s, 4); s += __shfl_xor(s, 8);
                if (fr == 0) rsum[wn * 256 + wm * 128 + m * 16 + fg * 4 + r] = s;
            }
        __syncthreads();
        if (tid < 256)
            partout[(size_t)bnIdx * NB + bm0 + tid] =
                rsum[tid] + rsum[256 + tid] + rsum[512 + tid] + rsum[768 + tid];
    }
}

// ---------------- per-row kernel: logits, losses, v ----------------
__global__ __launch_bounds__(256) void rows_kernel(const ushort_t* __restrict__ hb,
                                                   const int* __restrict__ y,
                                                   const float* __restrict__ W2,
                                                   const float* __restrict__ b2,
                                                   ushort_t* __restrict__ vb,
                                                   float4* __restrict__ rowstats) {
    __shared__ float w2s[NH * NC];
    __shared__ float b2s[NC];
    const int tid = threadIdx.x;
    for (int i = tid; i < NH * NC; i += 256) w2s[i] = W2[i];
    if (tid < NC) b2s[tid] = b2[tid];
    __syncthreads();
    const int wid = tid >> 6, lane = tid & 63;
    const int row = blockIdx.x * 4 + wid;
    const ushort_t* hrow = hb + (size_t)row * NH;
    ushort_t* vrow = vb + (size_t)row * NH;
    const int yi = y[row];
    float d0 = 0, d1 = 0, d2 = 0, d3 = 0, d4 = 0;
#pragma unroll
    for (int it = 0; it < 2; ++it) {
        const int n0 = it * 512 + lane * 8;
        u16x8 hv = *(const u16x8*)(hrow + n0);
        u16x8 ov;
#pragma unroll
        for (int j = 0; j < 8; ++j) {
            float hh = b2f(hv[j]);
            const float* wrow = &w2s[(n0 + j) * NC];
            d0 += hh * wrow[0]; d1 += hh * wrow[1]; d2 += hh * wrow[2];
            d3 += hh * wrow[3]; d4 += hh * wrow[4];
            ov[j] = f2b((1.f - hh * hh) * wrow[yi]);
        }
        *(u16x8*)(vrow + n0) = ov;
    }
#pragma unroll
    for (int off = 32; off; off >>= 1) {
        d0 += __shfl_xor(d0, off); d1 += __shfl_xor(d1, off); d2 += __shfl_xor(d2, off);
        d3 += __shfl_xor(d3, off); d4 += __shfl_xor(d4, off);
    }
    if (lane == 0) {
        float lg[NC] = { d0 + b2s[0], d1 + b2s[1], d2 + b2s[2], d3 + b2s[3], d4 + b2s[4] };
        float zy = lg[yi];
        float mse = 0.f, marg = 0.f;
        int amax = 0; float best = lg[0];
#pragma unroll
        for (int c = 0; c < NC; ++c) {
            float t = lg[c] - (c == yi ? 1.f : 0.f);
            mse += t * t;
            if (c != yi) marg += fmaxf(1.f - zy + lg[c], 0.f);
            if (lg[c] > best) { best = lg[c]; amax = c; }
        }
        rowstats[row] = make_float4(zy, mse, marg, (amax == yi) ? 1.f : 0.f);
    }
}

// ---------------- reductions ----------------
__global__ __launch_bounds__(256) void reduce_rows(const float4* __restrict__ rs,
                                                   const float* __restrict__ part,
                                                   int NT, float4* __restrict__ bsums) {
    const int tid = threadIdx.x;
    const int r = blockIdx.x * 256 + tid;
    float4 v = rs[r];
    float wl1 = 0.f;
    for (int t = 0; t < NT; ++t) wl1 += part[(size_t)t * NB + r];
    float R = wl1 * EPS_C / (fabsf(v.x) + 1e-8f);
    float4 s = make_float4(v.y, v.z, v.w, log1pf(R));
#pragma unroll
    for (int off = 32; off; off >>= 1) {
        s.x += __shfl_down(s.x, off); s.y += __shfl_down(s.y, off);
        s.z += __shfl_down(s.z, off); s.w += __shfl_down(s.w, off);
    }
    __shared__ float4 red[4];
    if ((tid & 63) == 0) red[tid >> 6] = s;
    __syncthreads();
    if (tid == 0) {
        float4 t = red[0];
        for (int i = 1; i < 4; ++i) { t.x += red[i].x; t.y += red[i].y; t.z += red[i].z; t.w += red[i].w; }
        bsums[blockIdx.x] = t;
    }
}

__global__ void final_combine(const float4* __restrict__ bsums, int nb, float* __restrict__ out) {
    if (threadIdx.x == 0) {
        float mse = 0, marg = 0, corr = 0, nsr = 0;
        for (int i = 0; i < nb; ++i) {
            float4 s = bsums[i];
            mse += s.x; marg += s.y; corr += s.z; nsr += s.w;
        }
        const float Bf = (float)NB;
        out[0] = mse / (Bf * (float)NC) + (marg / Bf + BETA * nsr / Bf) * (corr / Bf);
    }
}

extern "C" void kernel_launch(void* const* d_in, const int* in_sizes, int n_in,
                              void* d_out, int out_size, void* d_ws, size_t ws_size,
                              hipStream_t stream) {
    const float* x  = (const float*)d_in[0];
    const int*   y  = (const int*)d_in[1];
    const float* W1 = (const float*)d_in[2];
    const float* b1 = (const float*)d_in[3];
    const float* W2 = (const float*)d_in[4];
    const float* b2 = (const float*)d_in[5];
    float* out = (float*)d_out;

    char* ws = (char*)d_ws;
    ushort_t* W1Tb = (ushort_t*)(ws);                           // 4MB
    ushort_t* W1b  = (ushort_t*)(ws + (4ul << 20));             // 4MB
    ushort_t* xb   = (ushort_t*)(ws + (8ul << 20));             // 32MB
    ushort_t* hb   = (ushort_t*)(ws + (40ul << 20));            // 16MB
    ushort_t* vb   = (ushort_t*)(ws + (56ul << 20));            // 16MB
    float4*   rowstats = (float4*)(ws + (72ul << 20));          // 128KB
    float*    part = (float*)(ws + (72ul << 20) + (1ul << 20)); // 256KB
    float4*   bsums = (float4*)(ws + (74ul << 20));             // 512B

    // 1. conversions
    cvt_kernel<<<(NB * (long)NL) / (256 * 8), 256, 0, stream>>>(x, xb, (long)NB * NL);
    cvt_kernel<<<(NL * (long)NH) / (256 * 8), 256, 0, stream>>>(W1, W1b, (long)NL * NH);
    trans_kernel<<<dim3(NL / 32, NH / 32), 256, 0, stream>>>(W1, W1Tb);

    // 2. GEMM1: h = tanh(x @ W1 + b1)   [8192x1024], 256x128 tiles, 256 blocks
    gemm8p<0><<<256, 512, 0, stream>>>(xb, W1Tb, b1, hb, nullptr);

    // 3. per-row: logits/mse/margin/zy/correct + v
    rows_kernel<<<NB / 4, 256, 0, stream>>>(hb, y, W2, b2, vb, rowstats);

    // 4. GEMM2: g = v @ W1^T, row |.| partials   [8192x2048], 256x256 tiles, 256 blocks
    gemm8p<1><<<256, 512, 0, stream>>>(vb, W1b, nullptr, nullptr, part);

    // 5. reductions
    reduce_rows<<<NB / 256, 256, 0, stream>>>(rowstats, part, NL / 256, bsums);
    final_combine<<<1, 64, 0, stream>>>(bsums, NB / 256, out);
}

// Round 3
// 139.875 us; speedup vs baseline: 1.2808x; 1.2808x over previous
//
#include <hip/hip_runtime.h>
#include <hip/hip_bf16.h>

typedef unsigned short ushort_t;
typedef __attribute__((ext_vector_type(8))) short short8;
typedef __attribute__((ext_vector_type(8))) unsigned short u16x8;
typedef __attribute__((ext_vector_type(4))) float f32x4;

#define BETA 0.4f
#define EPS_C 0.05f
#define NB 8192
#define NH 1024
#define NL 2048
#define NC 5

static __device__ __forceinline__ float b2f(unsigned short u) {
    union { unsigned int i; float f; } x; x.i = ((unsigned int)u) << 16; return x.f;
}
static __device__ __forceinline__ unsigned short f2b(float f) {
    union { float f; unsigned int i; } x; x.f = f;
    unsigned int i = x.i;
    unsigned int r = (i + 0x7FFFu + ((i >> 16) & 1u)) >> 16;
    return (unsigned short)r;
}

static __device__ __forceinline__ void gload16(const ushort_t* g, ushort_t* l) {
    __builtin_amdgcn_global_load_lds((const __attribute__((address_space(1))) void*)g,
                                     (__attribute__((address_space(3))) void*)l, 16, 0, 0);
}

#define CFENCE() asm volatile("" ::: "memory")

// ---------------- conversion kernels ----------------
__global__ __launch_bounds__(256) void cvt_kernel(const float* __restrict__ in,
                                                  ushort_t* __restrict__ out, long n) {
    long i = ((long)blockIdx.x * 256 + threadIdx.x) * 8;
    if (i >= n) return;
    const float4 a = *(const float4*)(in + i);
    const float4 b = *(const float4*)(in + i + 4);
    u16x8 o;
    o[0] = f2b(a.x); o[1] = f2b(a.y); o[2] = f2b(a.z); o[3] = f2b(a.w);
    o[4] = f2b(b.x); o[5] = f2b(b.y); o[6] = f2b(b.z); o[7] = f2b(b.w);
    *(u16x8*)(out + i) = o;
}

// W1 [2048,1024] -> W1T bf16 [1024,2048]
__global__ __launch_bounds__(256) void trans_kernel(const float* __restrict__ W1,
                                                    ushort_t* __restrict__ W1Tb) {
    __shared__ float tile[32][33];
    const int tx = threadIdx.x & 31, ty = threadIdx.x >> 5;
    const int k0 = blockIdx.x * 32, n0 = blockIdx.y * 32;
#pragma unroll
    for (int i = 0; i < 4; ++i)
        tile[ty + i * 8][tx] = W1[(size_t)(k0 + ty + i * 8) * NH + n0 + tx];
    __syncthreads();
#pragma unroll
    for (int i = 0; i < 4; ++i)
        W1Tb[(size_t)(n0 + ty + i * 8) * NL + k0 + tx] = f2b(tile[tx][ty + i * 8]);
}

// ---------------- pipelined GEMM (C = A @ Bt^T), compile-time double-buffer ----------------
// EPI 0: GEMM1  A=[8192,2048] Bt=[1024,2048]  BM=256 BN=128, tanh epilogue -> hout
// EPI 1: GEMM2  A=[8192,1024] Bt=[2048,1024]  BM=256 BN=256, |.| row partials -> partout
template <int EPI>
__global__ __launch_bounds__(512, 2) void gemm8p(const ushort_t* __restrict__ A,
                                                 const ushort_t* __restrict__ Bt,
                                                 const float* __restrict__ b1,
                                                 ushort_t* __restrict__ hout,
                                                 float* __restrict__ partout) {
    constexpr int BN_T = (EPI == 0) ? 128 : 256;
    constexpr int K    = (EPI == 0) ? 2048 : 1024;
    constexpr int NOUT = (EPI == 0) ? 1024 : 2048;
    constexpr int NT   = K / 64;                 // K-tiles of 64 (32 / 16 — both even)
    constexpr int NPH  = (EPI == 0) ? 2 : 4;     // phases per K-tile
    constexpr int MPP  = 8 / NPH;                // m-frags per phase
    constexpr int NREP = BN_T / 64;              // n-frags per wave

    __shared__ ushort_t As[2][16384];            // 2 x 256x64 bf16 = 64 KB
    __shared__ ushort_t Bs[2][BN_T * 64];        // 32 or 64 KB

    const int tid = threadIdx.x;
    const int wv = tid >> 6, lane = tid & 63;
    const int wm = wv >> 2, wn = wv & 3;         // 2M x 4N waves
    const int fr = lane & 15, fg = lane >> 4;
    const int swz = (lane & 7) << 4;             // XOR swizzle bits (involution)
    const int cbb = fg << 4;

    // XCD-aware remap: XCD k owns a 4(bm) x 8(bn) sub-grid -> per-XCD L2 working set ~6-8MB
    const int xcd = blockIdx.x & 7, loc = blockIdx.x >> 3;   // loc 0..31
    const int bm0 = (xcd * 4 + (loc >> 3)) * 256;
    const int bnIdx = loc & 7;
    const int bn0 = bnIdx * BN_T;

    const int srow = lane >> 3;                       // staging row-in-8
    const int scol = ((lane & 7) ^ srow) << 3;        // pre-swizzled source col (elems)

    auto stA = [&](int buf, int kt, int half) {
#pragma unroll
        for (int c = 0; c < 2; ++c) {
            const int row = wv * 16 + c * 8 + srow;
            const ushort_t* g = A + (size_t)(bm0 + half * 128 + row) * K + kt * 64 + scol;
            gload16(g, &As[buf][half * 8192 + wv * 1024 + c * 512]);
        }
    };
    auto stB = [&](int buf, int kt, int half) {
#pragma unroll
        for (int c = 0; c < 2; ++c) {
            const int row = wv * 16 + c * 8 + srow;
            const ushort_t* g = Bt + (size_t)(bn0 + half * 128 + row) * K + kt * 64 + scol;
            gload16(g, &Bs[buf][half * 8192 + wv * 1024 + c * 512]);
        }
    };
    auto ldA = [&](int buf, int mf, int ks) -> short8 {
        const int rowt = wm * 128 + mf * 16 + fr;     // rowt&7 == lane&7
        return *(const short8*)((const char*)&As[buf][0] + rowt * 128 + (((ks << 6) + cbb) ^ swz));
    };
    auto ldB = [&](int buf, int nf, int ks) -> short8 {
        const int rowt = wn * (BN_T / 4) + nf * 16 + fr;
        return *(const short8*)((const char*)&Bs[buf][0] + rowt * 128 + (((ks << 6) + cbb) ^ swz));
    };

    f32x4 acc[8][NREP] = {};

    // prologue: stage K-tile 0 into buffer 0, drain, align
    stA(0, 0, 0); stA(0, 0, 1);
    stB(0, 0, 0);
    if constexpr (EPI == 1) stB(0, 0, 1);
    asm volatile("s_waitcnt vmcnt(0)" ::: "memory");
    CFENCE(); __builtin_amdgcn_s_barrier(); CFENCE();

    // TILE body: BUF is a LITERAL so LLVM can disambiguate As[BUF] reads from
    // As[BUF^1] gload_lds writes (no compiler-inserted vmcnt(0) drains).
#define TILEBODY(BUF, TT)                                                          \
    {                                                                              \
        const int ttv = (TT);                                                      \
        const bool more = ttv + 1 < NT;                                            \
        short8 bfl[NREP][2];                                                       \
        _Pragma("unroll")                                                          \
        for (int n = 0; n < NREP; ++n) {                                           \
            bfl[n][0] = ldB(BUF, n, 0);                                            \
            bfl[n][1] = ldB(BUF, n, 1);                                            \
        }                                                                          \
        _Pragma("unroll")                                                          \
        for (int p = 0; p < NPH; ++p) {                                            \
            short8 af[MPP][2];                                                     \
            _Pragma("unroll")                                                      \
            for (int i = 0; i < MPP; ++i) {                                        \
                af[i][0] = ldA(BUF, p * MPP + i, 0);                               \
                af[i][1] = ldA(BUF, p * MPP + i, 1);                               \
            }                                                                      \
            if (p == 0 && more) {                                                  \
                stA(BUF ^ 1, ttv + 1, 0);                                          \
                stA(BUF ^ 1, ttv + 1, 1);                                          \
                if constexpr (EPI == 0) stB(BUF ^ 1, ttv + 1, 0);                  \
            }                                                                      \
            if constexpr (EPI == 1)                                                \
                if (p == 1 && more) {                                              \
                    stB(BUF ^ 1, ttv + 1, 0);                                      \
                    stB(BUF ^ 1, ttv + 1, 1);                                      \
                }                                                                  \
            CFENCE(); __builtin_amdgcn_s_barrier(); CFENCE();                      \
            __builtin_amdgcn_s_setprio(1);                                         \
            _Pragma("unroll")                                                      \
            for (int i = 0; i < MPP; ++i) {                                        \
                _Pragma("unroll")                                                  \
                for (int n = 0; n < NREP; ++n) {                                   \
                    acc[p * MPP + i][n] = __builtin_amdgcn_mfma_f32_16x16x32_bf16( \
                        af[i][0], bfl[n][0], acc[p * MPP + i][n], 0, 0, 0);        \
                    acc[p * MPP + i][n] = __builtin_amdgcn_mfma_f32_16x16x32_bf16( \
                        af[i][1], bfl[n][1], acc[p * MPP + i][n], 0, 0, 0);        \
                }                                                                  \
            }                                                                      \
            __builtin_amdgcn_s_setprio(0);                                         \
            if (p == NPH - 1) asm volatile("s_waitcnt vmcnt(0)" ::: "memory");     \
            CFENCE(); __builtin_amdgcn_s_barrier(); CFENCE();                      \
        }                                                                          \
    }

#pragma unroll 1
    for (int t = 0; t < NT; t += 2) {
        TILEBODY(0, t)
        TILEBODY(1, t + 1)
    }
#undef TILEBODY

    if constexpr (EPI == 0) {
#pragma unroll
        for (int m = 0; m < 8; ++m)
#pragma unroll
            for (int n = 0; n < NREP; ++n) {
                const int col = bn0 + wn * 32 + n * 16 + fr;
                const float bb = b1[col];
                const size_t rbase = (size_t)(bm0 + wm * 128 + m * 16 + fg * 4) * NOUT + col;
#pragma unroll
                for (int r = 0; r < 4; ++r)
                    hout[rbase + (size_t)r * NOUT] = f2b(tanhf(acc[m][n][r] + bb));
            }
    } else {
        float* rsum = (float*)&As[0][0];  // LDS dead after K-loop; reuse (4 KB)
#pragma unroll
        for (int m = 0; m < 8; ++m)
#pragma unroll
            for (int r = 0; r < 4; ++r) {
                float s = 0.f;
#pragma unroll
                for (int n = 0; n < NREP; ++n) s += fabsf(acc[m][n][r]);
                s += __shfl_xor(s, 1); s += __shfl_xor(s, 2);
                s += __shfl_xor(s, 4); s += __shfl_xor(s, 8);
                if (fr == 0) rsum[wn * 256 + wm * 128 + m * 16 + fg * 4 + r] = s;
            }
        __syncthreads();
        if (tid < 256)
            partout[(size_t)bnIdx * NB + bm0 + tid] =
                rsum[tid] + rsum[256 + tid] + rsum[512 + tid] + rsum[768 + tid];
    }
}

// ---------------- per-row kernel: logits, losses, v ----------------
__global__ __launch_bounds__(256) void rows_kernel(const ushort_t* __restrict__ hb,
                                                   const int* __restrict__ y,
                                                   const float* __restrict__ W2,
                                                   const float* __restrict__ b2,
                                                   ushort_t* __restrict__ vb,
                                                   float4* __restrict__ rowstats) {
    __shared__ float w2s[NH * NC];
    __shared__ float b2s[NC];
    const int tid = threadIdx.x;
    for (int i = tid; i < NH * NC; i += 256) w2s[i] = W2[i];
    if (tid < NC) b2s[tid] = b2[tid];
    __syncthreads();
    const int wid = tid >> 6, lane = tid & 63;
    const int row = blockIdx.x * 4 + wid;
    const ushort_t* hrow = hb + (size_t)row * NH;
    ushort_t* vrow = vb + (size_t)row * NH;
    const int yi = y[row];
    float d0 = 0, d1 = 0, d2 = 0, d3 = 0, d4 = 0;
#pragma unroll
    for (int it = 0; it < 2; ++it) {
        const int n0 = it * 512 + lane * 8;
        u16x8 hv = *(const u16x8*)(hrow + n0);
        u16x8 ov;
#pragma unroll
        for (int j = 0; j < 8; ++j) {
            float hh = b2f(hv[j]);
            const float* wrow = &w2s[(n0 + j) * NC];
            d0 += hh * wrow[0]; d1 += hh * wrow[1]; d2 += hh * wrow[2];
            d3 += hh * wrow[3]; d4 += hh * wrow[4];
            ov[j] = f2b((1.f - hh * hh) * wrow[yi]);
        }
        *(u16x8*)(vrow + n0) = ov;
    }
#pragma unroll
    for (int off = 32; off; off >>= 1) {
        d0 += __shfl_xor(d0, off); d1 += __shfl_xor(d1, off); d2 += __shfl_xor(d2, off);
        d3 += __shfl_xor(d3, off); d4 += __shfl_xor(d4, off);
    }
    if (lane == 0) {
        float lg[NC] = { d0 + b2s[0], d1 + b2s[1], d2 + b2s[2], d3 + b2s[3], d4 + b2s[4] };
        float zy = lg[yi];
        float mse = 0.f, marg = 0.f;
        int amax = 0; float best = lg[0];
#pragma unroll
        for (int c = 0; c < NC; ++c) {
            float t = lg[c] - (c == yi ? 1.f : 0.f);
            mse += t * t;
            if (c != yi) marg += fmaxf(1.f - zy + lg[c], 0.f);
            if (lg[c] > best) { best = lg[c]; amax = c; }
        }
        rowstats[row] = make_float4(zy, mse, marg, (amax == yi) ? 1.f : 0.f);
    }
}

// ---------------- reductions ----------------
__global__ __launch_bounds__(256) void reduce_rows(const float4* __restrict__ rs,
                                                   const float* __restrict__ part,
                                                   int NT, float4* __restrict__ bsums) {
    const int tid = threadIdx.x;
    const int r = blockIdx.x * 256 + tid;
    float4 v = rs[r];
    float wl1 = 0.f;
    for (int t = 0; t < NT; ++t) wl1 += part[(size_t)t * NB + r];
    float R = wl1 * EPS_C / (fabsf(v.x) + 1e-8f);
    float4 s = make_float4(v.y, v.z, v.w, log1pf(R));
#pragma unroll
    for (int off = 32; off; off >>= 1) {
        s.x += __shfl_down(s.x, off); s.y += __shfl_down(s.y, off);
        s.z += __shfl_down(s.z, off); s.w += __shfl_down(s.w, off);
    }
    __shared__ float4 red[4];
    if ((tid & 63) == 0) red[tid >> 6] = s;
    __syncthreads();
    if (tid == 0) {
        float4 t = red[0];
        for (int i = 1; i < 4; ++i) { t.x += red[i].x; t.y += red[i].y; t.z += red[i].z; t.w += red[i].w; }
        bsums[blockIdx.x] = t;
    }
}

__global__ void final_combine(const float4* __restrict__ bsums, int nb, float* __restrict__ out) {
    if (threadIdx.x == 0) {
        float mse = 0, marg = 0, corr = 0, nsr = 0;
        for (int i = 0; i < nb; ++i) {
            float4 s = bsums[i];
            mse += s.x; marg += s.y; corr += s.z; nsr += s.w;
        }
        const float Bf = (float)NB;
        out[0] = mse / (Bf * (float)NC) + (marg / Bf + BETA * nsr / Bf) * (corr / Bf);
    }
}

extern "C" void kernel_launch(void* const* d_in, const int* in_sizes, int n_in,
                              void* d_out, int out_size, void* d_ws, size_t ws_size,
                              hipStream_t stream) {
    const float* x  = (const float*)d_in[0];
    const int*   y  = (const int*)d_in[1];
    const float* W1 = (const float*)d_in[2];
    const float* b1 = (const float*)d_in[3];
    const float* W2 = (const float*)d_in[4];
    const float* b2 = (const float*)d_in[5];
    float* out = (float*)d_out;

    char* ws = (char*)d_ws;
    ushort_t* W1Tb = (ushort_t*)(ws);                           // 4MB
    ushort_t* W1b  = (ushort_t*)(ws + (4ul << 20));             // 4MB
    ushort_t* xb   = (ushort_t*)(ws + (8ul << 20));             // 32MB
    ushort_t* hb   = (ushort_t*)(ws + (40ul << 20));            // 16MB
    ushort_t* vb   = (ushort_t*)(ws + (56ul << 20));            // 16MB
    float4*   rowstats = (float4*)(ws + (72ul << 20));          // 128KB
    float*    part = (float*)(ws + (72ul << 20) + (1ul << 20)); // 256KB
    float4*   bsums = (float4*)(ws + (74ul << 20));             // 512B

    // 1. conversions
    cvt_kernel<<<(NB * (long)NL) / (256 * 8), 256, 0, stream>>>(x, xb, (long)NB * NL);
    cvt_kernel<<<(NL * (long)NH) / (256 * 8), 256, 0, stream>>>(W1, W1b, (long)NL * NH);
    trans_kernel<<<dim3(NL / 32, NH / 32), 256, 0, stream>>>(W1, W1Tb);

    // 2. GEMM1: h = tanh(x @ W1 + b1)   [8192x1024], 256x128 tiles, 256 blocks
    gemm8p<0><<<256, 512, 0, stream>>>(xb, W1Tb, b1, hb, nullptr);

    // 3. per-row: logits/mse/margin/zy/correct + v
    rows_kernel<<<NB / 4, 256, 0, stream>>>(hb, y, W2, b2, vb, rowstats);

    // 4. GEMM2: g = v @ W1^T, row |.| partials   [8192x2048], 256x256 tiles, 256 blocks
    gemm8p<1><<<256, 512, 0, stream>>>(vb, W1b, nullptr, nullptr, part);

    // 5. reductions
    reduce_rows<<<NB / 256, 256, 0, stream>>>(rowstats, part, NL / 256, bsums);
    final_combine<<<1, 64, 0, stream>>>(bsums, NB / 256, out);
}